// Round 1
// baseline (673.599 us; speedup 1.0000x reference)
//
#include <hip/hip_runtime.h>

// DeepSetStrategyModel: E edges, C candidates, EMB=32, EDGE_DIM=1.
// Algebraic restructure (EDGE_DIM==1 => everything affine in scalar a_e):
//   U = wv@w_t1, V = bv@w_t1 + b_t1            (32 each)
//   g[c][k] = sum_{e in c} relu(a_e*U[k]+V[k]) (the only scatter)
//   S[c] = n_c*m0 + g[c]@M,  M = w_t2@w_u1_bot, m0 = b_t2@w_u1_bot
//   z2 = a*P + Q + S[src],  P = wv@w_u1_top, Q = bv@w_u1_top + b_u1
//   out = relu(z2)@w_u2 + b_u2

#define EMB 32

// ---------------- precompute fused constant vectors/matrices ----------------
// ws const layout (floats, relative to wsc):
//   [0,32)   U
//   [32,64)  V
//   [64,96)  P
//   [96,128) Q
//   [128,160) m0
//   [160,1184) M  (32x32, M[i][k] at 160+i*32+k)
__global__ void precompute_kernel(const float* __restrict__ w_v2h,
                                  const float* __restrict__ b_v2h,
                                  const float* __restrict__ w_t1,
                                  const float* __restrict__ b_t1,
                                  const float* __restrict__ w_t2,
                                  const float* __restrict__ b_t2,
                                  const float* __restrict__ w_u1,
                                  const float* __restrict__ b_u1,
                                  float* __restrict__ wsc) {
    int t = threadIdx.x;        // 0..1023
    int k = t & 31;
    int i = t >> 5;
    // M[i][k] = sum_j w_t2[i][j] * w_u1[32+j][k]
    float m = 0.f;
#pragma unroll
    for (int j = 0; j < 32; ++j)
        m = fmaf(w_t2[i * 32 + j], w_u1[(32 + j) * 32 + k], m);
    wsc[160 + i * 32 + k] = m;
    if (i == 0) {
        float u = 0.f, v = 0.f, p = 0.f, q = 0.f, m0 = 0.f;
#pragma unroll
        for (int j = 0; j < 32; ++j) {
            float wv = w_v2h[j];
            float bv = b_v2h[j];
            u  = fmaf(wv, w_t1[j * 32 + k], u);
            v  = fmaf(bv, w_t1[j * 32 + k], v);
            p  = fmaf(wv, w_u1[j * 32 + k], p);
            q  = fmaf(bv, w_u1[j * 32 + k], q);
            m0 = fmaf(b_t2[j], w_u1[(32 + j) * 32 + k], m0);
        }
        wsc[0 + k]   = u;
        wsc[32 + k]  = v + b_t1[k];
        wsc[64 + k]  = p;
        wsc[96 + k]  = q + b_u1[k];
        wsc[128 + k] = m0;
    }
}

// ---------------- phase 1: scatter g[c][k] += relu(a*U[k]+V[k]) -------------
// 32 lanes per edge => each wave's atomics hit 2 edges x 128B contiguous
// (4 cache lines), maximizing same-line merge in the TCC.
__global__ __launch_bounds__(256) void phase1_kernel(
        const float* __restrict__ attr,
        const int* __restrict__ src,
        const float* __restrict__ wsc,
        float* __restrict__ g,
        int* __restrict__ cnt,
        int E) {
    unsigned int gid = blockIdx.x * 256u + threadIdx.x;
    int e = (int)(gid >> 5);
    int k = (int)(gid & 31u);
    if (e >= E) return;
    float a = attr[e];
    int c = src[e];
    float r = fmaxf(fmaf(a, wsc[k], wsc[32 + k]), 0.f);
    unsafeAtomicAdd(&g[c * 32 + k], r);
    if (k == 0) atomicAdd(&cnt[c], 1);
}

// ---------------- per-candidate: S[c] = n_c*m0 + g[c]@M (in place) ----------
__global__ __launch_bounds__(256) void sscore_kernel(
        float* __restrict__ g,
        const int* __restrict__ cnt,
        const float* __restrict__ wsc,
        int C) {
    unsigned int gid = blockIdx.x * 256u + threadIdx.x;
    int c = (int)(gid >> 5);
    int k = (int)(gid & 31u);
    if (c >= C) return;
    float gk = g[c * 32 + k];
    float n = (float)cnt[c];
    float s = n * wsc[128 + k];
    const float* M = wsc + 160;
#pragma unroll
    for (int j = 0; j < 32; ++j) {
        float gj = __shfl(gk, j, 32);   // g[c][j] from lane j of the 32-group
        s = fmaf(gj, M[j * 32 + k], s);
    }
    g[c * 32 + k] = s;   // safe: every lane read its own g before any shfl use
}

// ---------------- phase 2: out[e] = relu(a*P+Q+S[src]) @ w_u2 + b_u2 --------
// One thread per edge; weights are wave-uniform => scalar (s_load) operands.
__global__ __launch_bounds__(256) void phase2_kernel(
        const float* __restrict__ attr,
        const int* __restrict__ src,
        const float* __restrict__ gs,     // S values (overwritten g)
        const float* __restrict__ wsc,
        const float* __restrict__ w_u2,
        const float* __restrict__ b_u2,
        float* __restrict__ out,
        int E) {
    int e = blockIdx.x * 256 + threadIdx.x;
    if (e >= E) return;
    float a = attr[e];
    int c = src[e];
    const float4* Sv = (const float4*)(gs + (size_t)c * 32);

    float r[32];
#pragma unroll
    for (int q = 0; q < 8; ++q) {
        float4 s4 = Sv[q];
        int k = q * 4;
        r[k + 0] = fmaxf(fmaf(a, wsc[64 + k + 0], wsc[96 + k + 0]) + s4.x, 0.f);
        r[k + 1] = fmaxf(fmaf(a, wsc[64 + k + 1], wsc[96 + k + 1]) + s4.y, 0.f);
        r[k + 2] = fmaxf(fmaf(a, wsc[64 + k + 2], wsc[96 + k + 2]) + s4.z, 0.f);
        r[k + 3] = fmaxf(fmaf(a, wsc[64 + k + 3], wsc[96 + k + 3]) + s4.w, 0.f);
    }

    float acc[32];
#pragma unroll
    for (int m = 0; m < 32; ++m) acc[m] = b_u2[m];
#pragma unroll
    for (int k = 0; k < 32; ++k) {
#pragma unroll
        for (int m = 0; m < 32; ++m)
            acc[m] = fmaf(r[k], w_u2[k * 32 + m], acc[m]);
    }

    float4* o = (float4*)(out + (size_t)e * 32);
#pragma unroll
    for (int q = 0; q < 8; ++q)
        o[q] = make_float4(acc[q * 4 + 0], acc[q * 4 + 1],
                           acc[q * 4 + 2], acc[q * 4 + 3]);
}

extern "C" void kernel_launch(void* const* d_in, const int* in_sizes, int n_in,
                              void* d_out, int out_size, void* d_ws, size_t ws_size,
                              hipStream_t stream) {
    const float* attr   = (const float*)d_in[0];
    const int*   eidx   = (const int*)d_in[1];   // int64 -> int32 on device; src = first E
    const float* w_v2h  = (const float*)d_in[3];
    const float* b_v2h  = (const float*)d_in[4];
    const float* w_t1   = (const float*)d_in[5];
    const float* b_t1   = (const float*)d_in[6];
    const float* w_t2   = (const float*)d_in[7];
    const float* b_t2   = (const float*)d_in[8];
    const float* w_u1   = (const float*)d_in[9];
    const float* b_u1   = (const float*)d_in[10];
    const float* w_u2   = (const float*)d_in[11];
    const float* b_u2   = (const float*)d_in[12];
    float* out = (float*)d_out;

    int E = in_sizes[0];          // edge_attr is E x 1
    int C = in_sizes[2];          // candidate_idxs length

    // ws layout: g/S (C*32 f32) | cnt (C i32) | wsc (consts, 1184 f32)
    float* ws  = (float*)d_ws;
    float* g   = ws;
    int*   cnt = (int*)(ws + (size_t)C * 32);
    size_t wsc_off = (((size_t)C * 33 + 31) / 32) * 32;   // 128B-aligned
    float* wsc = ws + wsc_off;

    // zero g + cnt (ws is re-poisoned to 0xAA before every timed call)
    hipMemsetAsync(g, 0, (size_t)C * 32 * 4 + (size_t)C * 4, stream);

    precompute_kernel<<<1, 1024, 0, stream>>>(w_v2h, b_v2h, w_t1, b_t1,
                                              w_t2, b_t2, w_u1, b_u1, wsc);

    unsigned int n1 = (unsigned int)E * 32u;
    phase1_kernel<<<(n1 + 255) / 256, 256, 0, stream>>>(attr, eidx, wsc, g, cnt, E);

    sscore_kernel<<<((unsigned)C * 32u + 255) / 256, 256, 0, stream>>>(g, cnt, wsc, C);

    phase2_kernel<<<((unsigned)E + 255) / 256, 256, 0, stream>>>(attr, eidx, g, wsc,
                                                                 w_u2, b_u2, out, E);
}